// Round 17
// baseline (68.096 us; speedup 1.0000x reference)
//
#include <hip/hip_runtime.h>
#include <math.h>

typedef unsigned long long u64;
typedef __attribute__((ext_vector_type(8))) short bf16x8;
typedef __attribute__((ext_vector_type(4))) float f32x4;

#define S_DIM 1023
#define B_DIM 64
#define I_DIM 1024
#define CTX_DIM 784
#define CTX4 196          // CTX_DIM / 4
#define NWROWS 16         // 2^M buckets
#define HROWS 8           // rows per half-tile
#define NHALF (S_DIM * 2) // 2046 half-tiles
#define G_S 4             // half-tiles per block (pipelined)

#define LR_C 0.01f
#define WC_C 5.0f
#define LO_C (-6.906754778648554f)
#define HI_C ( 6.906754778648554f)

__device__ __forceinline__ float dot4(float4 a, float4 b) {
    return a.x * b.x + a.y * b.y + a.z * b.z + a.w * b.w;
}

__device__ __forceinline__ float4 upd4(float4 w, float4 a, float c) {
    float4 r;
    r.x = fminf(fmaxf(w.x - c * a.x, -WC_C), WC_C);
    r.y = fminf(fmaxf(w.y - c * a.y, -WC_C), WC_C);
    r.z = fminf(fmaxf(w.z - c * a.z, -WC_C), WC_C);
    r.w = fminf(fmaxf(w.w - c * a.w, -WC_C), WC_C);
    return r;
}

__device__ __forceinline__ short f2bf(float f) {
    union { float f; unsigned u; } cv; cv.f = f;
    unsigned r = cv.u + 0x7fffu + ((cv.u >> 16) & 1u);   // RNE
    return (short)(r >> 16);
}

__device__ __forceinline__ float bf2f(short h) {
    union { unsigned u; float f; } cv;
    cv.u = ((unsigned)(unsigned short)h) << 16;
    return cv.f;
}

// ---------------- kernel 0: DIAGNOSTIC control -- pure f4 copy of half of W ----------------
// Writes weights values into new_weights[0 .. 512 s); the body kernel later
// overwrites ALL of new_weights, so output is unaffected. Its rocprof row
// measures the practical mixed read+write stream ceiling.
__global__ __launch_bounds__(256) void ctrl_copy_kernel(
    const float4* __restrict__ src, float4* __restrict__ dst)
{
    const int g = blockIdx.x * 256 + threadIdx.x;       // 524288 threads
    #pragma unroll
    for (int k = 0; k < 4; ++k) {
        int i = g + k * 524288;                         // 2,097,152 f4 = 33.5 MB
        dst[i] = src[i];
    }
}

// ---------------- kernel 1: prep (49 blocks) + pack (32 blocks) ----------------
__global__ __launch_bounds__(256) void prep_pack_kernel(
    const float* __restrict__ context,   // [B, CTX]
    const float* __restrict__ bias,      // [1]
    const float* __restrict__ logit,     // [B, I]
    float4* __restrict__ ctxT4,          // [CTX4][B]
    short* __restrict__ pack_b,          // [4*32*64*8]
    float* __restrict__ out_logits)      // [B, S+1]
{
    const int blk = blockIdx.x;
    const int t = threadIdx.x;
    if (blk < 49) {
        int g = blk * 256 + t;
        int k4 = g >> 6;
        int b  = g & 63;
        ctxT4[g] = *(const float4*)(context + (size_t)b * CTX_DIM + k4 * 4);
        if (g < B_DIM) out_logits[(size_t)g * (S_DIM + 1)] = bias[0];
    } else {
        int g = (blk - 49) * 256 + t;
        int l  = g & 63;
        int kb = (g >> 6) & 31;
        int nt = g >> 11;
        int b  = nt * 16 + (l & 15);
        int i0 = kb * 32 + (l >> 4) * 8;
        const float* src = logit + (size_t)b * I_DIM + i0;
        bf16x8 v;
        #pragma unroll
        for (int j = 0; j < 8; ++j) v[j] = f2bf(src[j]);
        *(bf16x8*)(pack_b + (size_t)g * 8) = v;
    }
}

// ---------------- kernel 2: standalone halfspace hash -> membership masks ----------------
__global__ __launch_bounds__(256) void gln_idx_kernel(
    const float* __restrict__ cm,        // [S, 4, CTX]
    const float* __restrict__ cb,        // [S, 4]
    const float4* __restrict__ ctxT4,    // [CTX4][B]
    u64* __restrict__ mask_g)            // [S*16]
{
    __shared__ float red[4][4][64];
    __shared__ int   bits[4][64];
    __shared__ float cb_lds[4];

    const int s = blockIdx.x;
    const int t = threadIdx.x;
    if (t < 4) cb_lds[t] = cb[s * 4 + t];

    const int b = t & 63;
    const int q = __builtin_amdgcn_readfirstlane(t >> 6);
    const float4* cmr = (const float4*)(cm + (size_t)s * 4 * CTX_DIM);

    float a0 = 0.f, a1 = 0.f, a2 = 0.f, a3 = 0.f;
    const int k0 = q * 49;
    #pragma unroll 7
    for (int kk = 0; kk < 49; ++kk) {
        int k4 = k0 + kk;
        float4 c4 = ctxT4[k4 * 64 + b];
        a0 += dot4(cmr[k4], c4);
        a1 += dot4(cmr[CTX4 + k4], c4);
        a2 += dot4(cmr[2 * CTX4 + k4], c4);
        a3 += dot4(cmr[3 * CTX4 + k4], c4);
    }
    red[q][0][b] = a0;
    red[q][1][b] = a1;
    red[q][2][b] = a2;
    red[q][3][b] = a3;
    __syncthreads();

    {
        int m = t >> 6, bb = t & 63;
        float sum = red[0][m][bb] + red[1][m][bb] + red[2][m][bb] + red[3][m][bb];
        bits[m][bb] = (sum > cb_lds[m]) ? 1 : 0;
    }
    __syncthreads();

    if (t < B_DIM) {
        int v = bits[0][t] + 2 * bits[1][t] + 4 * bits[2][t] + 8 * bits[3][t];
        u64 my = 0;
        #pragma unroll
        for (int kk = 0; kk < NWROWS; ++kk) {
            u64 mk = __ballot(v == kk);
            if (t == kk) my = mk;
        }
        if (t < NWROWS) mask_g[s * NWROWS + t] = my;
    }
}

// ---------------- kernel 3: pipelined body -- G_S half-tiles per block ----------------
// Double-buffered 16KB bf16 tiles. Per iteration: MFMA+selection(cur) | B1 |
// issue next tile's loads EARLY, update(cur) stores overlap the load returns,
// cvt+ds_write LATE | B2. Stage reads of h+1 mix with update writes of h.
__global__ __launch_bounds__(256, 4) void gln_pipe_kernel(
    const float* __restrict__ logit,     // [B, I] fp32
    const float* __restrict__ target,    // [B]
    const float* __restrict__ weights,   // [S, 16, I] fp32
    const u64*   __restrict__ mask_g,    // [S*16] == [NHALF*8]
    const short* __restrict__ pack_b,    // bf16 B-fragments
    float* __restrict__ out_logits,      // [B, S+1]
    float* __restrict__ new_weights)     // [S, 16, I]
{
    __shared__ short Abf[2][HROWS * I_DIM];   // 2 x 16 KB swizzled bf16 tiles
    __shared__ u64   mask_lds[2][HROWS];
    __shared__ int   lastb_lds[2][HROWS];
    __shared__ float coef_lds[2][HROWS];

    const int t  = threadIdx.x;
    const int wv = t >> 6;
    const int l  = t & 63;
    const int h0 = blockIdx.x * G_S;

    const float4* L4 = (const float4*)logit;

    // ---- prologue: stage tile h0 into buf 0, load its masks ----
    {
        const int h = h0;                                // h0 < 2046 always (grid=512 -> h0<=2044)
        const float4* W4 = (const float4*)weights + (size_t)h * (HROWS * 256);
        float4 ld[8];
        #pragma unroll
        for (int j = 0; j < HROWS; ++j) ld[j] = W4[t + j * 256];
        if (t < HROWS) {
            u64 m = mask_g[(size_t)h * HROWS + t];
            mask_lds[0][t]  = m;
            lastb_lds[0][t] = m ? (63 - __clzll(m)) : -1;
        }
        #pragma unroll
        for (int j = 0; j < HROWS; ++j) {
            int slot = j * 128 + ((t >> 1) ^ j);
            short4 v;
            v.x = f2bf(ld[j].x); v.y = f2bf(ld[j].y);
            v.z = f2bf(ld[j].z); v.w = f2bf(ld[j].w);
            *(short4*)(&Abf[0][0] + slot * 8 + (t & 1) * 4) = v;
        }
    }
    __syncthreads();

    const int row_local = l & 7;
    const int q2  = l >> 4;
    const int base_slot = row_local * 128;
    const bf16x8* Bb = (const bf16x8*)pack_b + (size_t)wv * 2048 + l;
    const int col = wv * 16 + (l & 15);

    for (int g = 0; g < G_S; ++g) {
        const int h = h0 + g;
        const bool valid = (h < NHALF);
        const int cur = g & 1;
        const int s = h >> 1;

        // ---- MFMA + selection on buf[cur] ----
        if (valid) {
            f32x4 acc = {0.f, 0.f, 0.f, 0.f};
            const short* A = &Abf[cur][0];
            #pragma unroll 8
            for (int kb = 0; kb < 32; ++kb) {
                bf16x8 af = *(const bf16x8*)(A + 8 * (base_slot + ((kb * 4 + q2) ^ row_local)));
                bf16x8 bfr = Bb[(size_t)kb * 64];
                acc = __builtin_amdgcn_mfma_f32_16x16x32_bf16(af, bfr, acc, 0, 0, 0);
            }
            if (q2 < 2) {
                #pragma unroll
                for (int j = 0; j < 4; ++j) {
                    int r = q2 * 4 + j;
                    u64 m = mask_lds[cur][r];
                    if ((m >> col) & 1) {
                        float o = fminf(fmaxf(acc[j], LO_C), HI_C);
                        out_logits[(size_t)col * (S_DIM + 1) + s + 1] = o;
                        if (col == lastb_lds[cur][r])
                            coef_lds[cur][r] = LR_C * (1.0f / (1.0f + expf(-o)) - target[col]);
                    }
                }
            }
        }
        __syncthreads();   // B1: coef visible; nothing in vmcnt

        // ---- issue next tile's loads EARLY ----
        const int hn = h + 1;
        const bool nvalid = (g + 1 < G_S) && (hn < NHALF);
        float4 ld[8];
        if (nvalid) {
            const float4* W4n = (const float4*)weights + (size_t)hn * (HROWS * 256);
            #pragma unroll
            for (int j = 0; j < HROWS; ++j) ld[j] = W4n[t + j * 256];
            if (t < HROWS) {
                u64 m = mask_g[(size_t)hn * HROWS + t];
                mask_lds[cur ^ 1][t]  = m;
                lastb_lds[cur ^ 1][t] = m ? (63 - __clzll(m)) : -1;
            }
        }

        // ---- update(cur): LDS read + L2 logit read + stores; overlaps ld returns ----
        if (valid) {
            float4* D4 = (float4*)new_weights + (size_t)h * (HROWS * 256);
            const short* A = &Abf[cur][0];
            #pragma unroll 4
            for (int r = 0; r < HROWS; ++r) {
                const int lb = lastb_lds[cur][r];
                int slot = r * 128 + ((t >> 1) ^ r);
                short4 v = *(const short4*)(A + slot * 8 + (t & 1) * 4);
                float4 w;
                w.x = bf2f(v.x); w.y = bf2f(v.y); w.z = bf2f(v.z); w.w = bf2f(v.w);
                float4 o;
                if (lb < 0) {
                    o = w;
                } else {
                    o = upd4(w, L4[lb * 256 + t], coef_lds[cur][r]);
                }
                D4[r * 256 + t] = o;
            }
        }

        // ---- write next tile LATE (vmcnt waits here, mostly satisfied) ----
        if (nvalid) {
            #pragma unroll
            for (int j = 0; j < HROWS; ++j) {
                int slot = j * 128 + ((t >> 1) ^ j);
                short4 v;
                v.x = f2bf(ld[j].x); v.y = f2bf(ld[j].y);
                v.z = f2bf(ld[j].z); v.w = f2bf(ld[j].w);
                *(short4*)(&Abf[cur ^ 1][0] + slot * 8 + (t & 1) * 4) = v;
            }
        }
        __syncthreads();   // B2: next tile ready
    }
}

extern "C" void kernel_launch(void* const* d_in, const int* in_sizes, int n_in,
                              void* d_out, int out_size, void* d_ws, size_t ws_size,
                              hipStream_t stream) {
    const float* logit   = (const float*)d_in[0];   // [B, I, 1]
    const float* context = (const float*)d_in[1];   // [B, CTX]
    const float* target  = (const float*)d_in[2];   // [B, 1]
    const float* cm      = (const float*)d_in[3];   // [1, S, 4, CTX]
    const float* cb      = (const float*)d_in[4];   // [1, S, 4, 1]
    const float* weights = (const float*)d_in[5];   // [1, S, 16, I]
    const float* bias    = (const float*)d_in[6];   // [1]

    float* out_logits  = (float*)d_out;                       // [B, S+1]
    float* new_weights = out_logits + (size_t)B_DIM * (S_DIM + 1);

    char* ws = (char*)d_ws;
    float4* ctxT4  = (float4*)ws;    ws += (size_t)CTX4 * B_DIM * 16;   // 200704 B
    short*  packb  = (short*)ws;     ws += (size_t)4 * 32 * 64 * 8 * 2; // 131072 B
    u64*    mask_g = (u64*)ws;                                          // 130944 B

    ctrl_copy_kernel<<<2048, 256, 0, stream>>>((const float4*)weights,
                                               (float4*)new_weights);
    prep_pack_kernel<<<81, 256, 0, stream>>>(context, bias, logit, ctxT4, packb, out_logits);
    gln_idx_kernel<<<S_DIM, 256, 0, stream>>>(cm, cb, ctxT4, mask_g);
    gln_pipe_kernel<<<(NHALF + G_S - 1) / G_S, 256, 0, stream>>>(
        logit, target, weights, mask_g, packb, out_logits, new_weights);
}

// Round 18
// 64.281 us; speedup vs baseline: 1.0594x; 1.0594x over previous
//
#include <hip/hip_runtime.h>
#include <math.h>

typedef unsigned long long u64;
typedef __attribute__((ext_vector_type(8))) short bf16x8;
typedef __attribute__((ext_vector_type(4))) float f32x4;

#define S_DIM 1023
#define B_DIM 64
#define I_DIM 1024
#define CTX_DIM 784
#define CTX4 196          // CTX_DIM / 4
#define NWROWS 16         // 2^M buckets
#define NTASK (S_DIM * NWROWS)

#define LR_C 0.01f
#define WC_C 5.0f
#define LO_C (-6.906754778648554f)
#define HI_C ( 6.906754778648554f)

__device__ __forceinline__ float dot4(float4 a, float4 b) {
    return a.x * b.x + a.y * b.y + a.z * b.z + a.w * b.w;
}

__device__ __forceinline__ float4 upd4(float4 w, float4 a, float c) {
    float4 r;
    r.x = fminf(fmaxf(w.x - c * a.x, -WC_C), WC_C);
    r.y = fminf(fmaxf(w.y - c * a.y, -WC_C), WC_C);
    r.z = fminf(fmaxf(w.z - c * a.z, -WC_C), WC_C);
    r.w = fminf(fmaxf(w.w - c * a.w, -WC_C), WC_C);
    return r;
}

__device__ __forceinline__ short f2bf(float f) {
    union { float f; unsigned u; } cv; cv.f = f;
    unsigned r = cv.u + 0x7fffu + ((cv.u >> 16) & 1u);   // RNE
    return (short)(r >> 16);
}

// ---------------- kernel 1: prep (49 blocks) + pack (32 blocks) ----------------
__global__ __launch_bounds__(256) void prep_pack_kernel(
    const float* __restrict__ context,   // [B, CTX]
    const float* __restrict__ bias,      // [1]
    const float* __restrict__ logit,     // [B, I]
    float4* __restrict__ ctxT4,          // [CTX4][B]
    short* __restrict__ pack_b,          // [4*32*64*8]
    float* __restrict__ out_logits)      // [B, S+1]
{
    const int blk = blockIdx.x;
    const int t = threadIdx.x;
    if (blk < 49) {
        int g = blk * 256 + t;
        int k4 = g >> 6;
        int b  = g & 63;
        ctxT4[g] = *(const float4*)(context + (size_t)b * CTX_DIM + k4 * 4);
        if (g < B_DIM) out_logits[(size_t)g * (S_DIM + 1)] = bias[0];
    } else {
        int g = (blk - 49) * 256 + t;
        int l  = g & 63;
        int kb = (g >> 6) & 31;
        int nt = g >> 11;
        int b  = nt * 16 + (l & 15);
        int i0 = kb * 32 + (l >> 4) * 8;
        const float* src = logit + (size_t)b * I_DIM + i0;
        bf16x8 v;
        #pragma unroll
        for (int j = 0; j < 8; ++j) v[j] = f2bf(src[j]);
        *(bf16x8*)(pack_b + (size_t)g * 8) = v;
    }
}

// ---------------- kernel 2 (D): stage+idx+MFMA+selection -- READ-ONLY HBM ----------------
// W is read once (the only HBM W read in the whole pipeline) and staged to LDS;
// the idx phase (VALU/L2-bound) runs in the shadow of other blocks' read bursts;
// output is only the tiny coef/lastb tables + out_logits entries.
__global__ __launch_bounds__(256, 4) void gln_dots_kernel(
    const float* __restrict__ logit,     // [B, I] fp32
    const float* __restrict__ target,    // [B]
    const float* __restrict__ weights,   // [S, 16, I] fp32
    const float* __restrict__ cm,        // [S, 4, CTX]
    const float* __restrict__ cb,        // [S, 4]
    const float4* __restrict__ ctxT4,    // [CTX4][B]
    const short* __restrict__ pack_b,    // bf16 B-fragments
    float* __restrict__ out_logits,      // [B, S+1]
    int*   __restrict__ lastb_g,         // [S*16]
    float* __restrict__ coef_g)          // [S*16]
{
    __shared__ short Abf[NWROWS * I_DIM];   // 32 KB swizzled bf16 W[s]
    __shared__ float red[4][4][64];         // [q][m][b]
    __shared__ int   bits[4][64];
    __shared__ float cb_lds[4];
    __shared__ u64   mask_lds[NWROWS];
    __shared__ int   lastb_lds[NWROWS];

    const int s  = blockIdx.x;
    const int t  = threadIdx.x;
    const int wv = t >> 6;
    const int l  = t & 63;

    if (t < 4) cb_lds[t] = cb[s * 4 + t];

    // ---- stage FIRST: loads consumed immediately -> read burst starts at t=0 ----
    const float4* W4 = (const float4*)(weights + (size_t)s * (NWROWS * I_DIM));
    #pragma unroll
    for (int j = 0; j < NWROWS; ++j) {
        float4 w = W4[t + j * 256];              // row j, cols 4t..4t+3
        int slot = j * 128 + ((t >> 1) ^ (j & 7));
        short4 v;
        v.x = f2bf(w.x); v.y = f2bf(w.y); v.z = f2bf(w.z); v.w = f2bf(w.w);
        *(short4*)(Abf + slot * 8 + (t & 1) * 4) = v;   // ds_write_b64
    }

    // ---- idx phase (no dependence on Abf; overlaps other blocks' reads) ----
    {
        const int b = t & 63;
        const int q = __builtin_amdgcn_readfirstlane(t >> 6);
        const float4* cmr = (const float4*)(cm + (size_t)s * 4 * CTX_DIM);
        float a0 = 0.f, a1 = 0.f, a2 = 0.f, a3 = 0.f;
        const int k0 = q * 49;
        #pragma unroll 7
        for (int kk = 0; kk < 49; ++kk) {
            int k4 = k0 + kk;
            float4 c4 = ctxT4[k4 * 64 + b];
            a0 += dot4(cmr[k4], c4);
            a1 += dot4(cmr[CTX4 + k4], c4);
            a2 += dot4(cmr[2 * CTX4 + k4], c4);
            a3 += dot4(cmr[3 * CTX4 + k4], c4);
        }
        red[q][0][b] = a0;
        red[q][1][b] = a1;
        red[q][2][b] = a2;
        red[q][3][b] = a3;
    }
    __syncthreads();
    {
        int m = t >> 6, bb = t & 63;
        float sum = red[0][m][bb] + red[1][m][bb] + red[2][m][bb] + red[3][m][bb];
        bits[m][bb] = (sum > cb_lds[m]) ? 1 : 0;
    }
    __syncthreads();
    if (t < B_DIM) {   // wave 0: lane = b
        int v = bits[0][t] + 2 * bits[1][t] + 4 * bits[2][t] + 8 * bits[3][t];
        u64 my = 0;
        #pragma unroll
        for (int kk = 0; kk < NWROWS; ++kk) {
            u64 mk = __ballot(v == kk);
            if (t == kk) my = mk;
        }
        if (t < NWROWS) {
            int lb = my ? (63 - __clzll(my)) : -1;
            mask_lds[t]  = my;
            lastb_lds[t] = lb;
            lastb_g[s * NWROWS + t] = lb;
        }
    }
    __syncthreads();

    // ---- MFMA: P[16][64] = W[s] . logit^T; wave wv -> cols wv*16..+15 ----
    const int row = l & 15;
    const int q2  = l >> 4;
    const int sw  = row & 7;
    const int base_slot = row * 128;
    const bf16x8* Bb = (const bf16x8*)pack_b + (size_t)wv * 2048 + l;
    f32x4 acc = {0.f, 0.f, 0.f, 0.f};
    #pragma unroll 8
    for (int kb = 0; kb < 32; ++kb) {
        bf16x8 af = *(const bf16x8*)(Abf + 8 * (base_slot + ((kb * 4 + q2) ^ sw)));
        bf16x8 bfr = Bb[(size_t)kb * 64];
        acc = __builtin_amdgcn_mfma_f32_16x16x32_bf16(af, bfr, acc, 0, 0, 0);
    }

    // ---- selection: out[b] = P[idx[b]][b]; coef for last-b of each row ----
    const int col = wv * 16 + (l & 15);
    #pragma unroll
    for (int j = 0; j < 4; ++j) {
        int r = q2 * 4 + j;                      // C-layout: col=l&15, row=(l>>4)*4+j
        u64 m = mask_lds[r];
        if ((m >> col) & 1) {
            float o = fminf(fmaxf(acc[j], LO_C), HI_C);
            out_logits[(size_t)col * (S_DIM + 1) + s + 1] = o;
            if (col == lastb_lds[r])
                coef_g[s * NWROWS + r] = LR_C * (1.0f / (1.0f + expf(-o)) - target[col]);
        }
    }
}

// ---------------- kernel 3 (E): pure streaming update -- ctrl_copy-shaped ----------------
// W re-read is served by L3 (D just streamed all of W through it); stores are
// fire-and-forget; no LDS, no barriers, 2 independent RMW chains per thread.
__global__ __launch_bounds__(256) void gln_upd_kernel(
    const float* __restrict__ logit,     // [B, I]
    const float* __restrict__ weights,   // [S*16*I]
    const int*   __restrict__ lastb_g,   // [S*16]
    const float* __restrict__ coef_g,    // [S*16]
    float* __restrict__ new_weights)
{
    const int total = NTASK * 256;       // float4 count
    const int stride = gridDim.x * 256;
    for (int g = blockIdx.x * 256 + threadIdx.x; g < total; g += stride) {
        const int task = g >> 8;
        const int off  = g & 255;
        const int lb   = lastb_g[task];          // wave-uniform (256 f4 per task)
        float4 w = ((const float4*)weights)[g];
        float4 r;
        if (lb < 0) {
            r = w;
        } else {
            const float c = coef_g[task];
            float4 a = ((const float4*)logit)[lb * 256 + off];
            r = upd4(w, a, c);
        }
        ((float4*)new_weights)[g] = r;
    }
}

extern "C" void kernel_launch(void* const* d_in, const int* in_sizes, int n_in,
                              void* d_out, int out_size, void* d_ws, size_t ws_size,
                              hipStream_t stream) {
    const float* logit   = (const float*)d_in[0];   // [B, I, 1]
    const float* context = (const float*)d_in[1];   // [B, CTX]
    const float* target  = (const float*)d_in[2];   // [B, 1]
    const float* cm      = (const float*)d_in[3];   // [1, S, 4, CTX]
    const float* cb      = (const float*)d_in[4];   // [1, S, 4, 1]
    const float* weights = (const float*)d_in[5];   // [1, S, 16, I]
    const float* bias    = (const float*)d_in[6];   // [1]

    float* out_logits  = (float*)d_out;                       // [B, S+1]
    float* new_weights = out_logits + (size_t)B_DIM * (S_DIM + 1);

    char* ws = (char*)d_ws;
    float4* ctxT4   = (float4*)ws;   ws += (size_t)CTX4 * B_DIM * 16;   // 200704 B
    short*  packb   = (short*)ws;    ws += (size_t)4 * 32 * 64 * 8 * 2; // 131072 B
    int*    lastb_g = (int*)ws;      ws += (size_t)NTASK * 4;           //  65472 B
    float*  coef_g  = (float*)ws;                                       //  65472 B

    prep_pack_kernel<<<81, 256, 0, stream>>>(context, bias, logit, ctxT4, packb, out_logits);
    gln_dots_kernel<<<S_DIM, 256, 0, stream>>>(logit, target, weights, cm, cb,
                                               ctxT4, packb, out_logits,
                                               lastb_g, coef_g);
    gln_upd_kernel<<<8192, 256, 0, stream>>>(logit, weights, lastb_g, coef_g, new_weights);
}